// Round 3
// baseline (317.627 us; speedup 1.0000x reference)
//
#include <hip/hip_runtime.h>
#include <hip/hip_bf16.h>

#define HEADS 8
#define CPH   128
#define NEG   0.2f

// ---------------- CSR build (counting sort by dst) ----------------
__global__ void k_zero(int* p, int n) {
    int i = blockIdx.x * blockDim.x + threadIdx.x;
    if (i < n) p[i] = 0;
}

__global__ void k_count(const int* __restrict__ dst, int E, int N, int* counts) {
    int e = blockIdx.x * blockDim.x + threadIdx.x;
    if (e < E + N) {
        int d = (e < E) ? dst[e] : (e - E);   // self-loops appended
        atomicAdd(&counts[d], 1);
    }
}

// single block, 256 threads: inclusive scan of counts -> offs (exclusive) + cursor
__global__ void k_scan(const int* __restrict__ counts, int* offs, int* cursor, int N) {
    __shared__ int buf[256];
    int t = threadIdx.x;
    int v = (t < N) ? counts[t] : 0;
    buf[t] = v;
    __syncthreads();
    for (int off = 1; off < 256; off <<= 1) {
        int add = (t >= off) ? buf[t - off] : 0;
        __syncthreads();
        buf[t] += add;
        __syncthreads();
    }
    if (t == 0) offs[0] = 0;
    if (t < N) {
        offs[t + 1] = buf[t];
        cursor[t]   = buf[t] - v;   // exclusive prefix
    }
}

__global__ void k_scatter(const int* __restrict__ srcA, const int* __restrict__ dstA,
                          int E, int N, int* cursor, int* __restrict__ srcs) {
    int e = blockIdx.x * blockDim.x + threadIdx.x;
    if (e < E + N) {
        int d = (e < E) ? dstA[e] : (e - E);
        int s = (e < E) ? srcA[e] : (e - E);
        int pos = atomicAdd(&cursor[d], 1);
        srcs[pos] = s;
    }
}

// ---------------- fused dual GEMM: out[:, :1024]=X@Wl^T+bl, out[:,1024:]=X@Wr^T+br ----
#define BM 32
#define BN 64
#define BK 32
#define XP 34   // xs row stride (pad, 8B-aligned float2 reads)
#define WP 68   // ws row stride (pad, 16B-aligned float4 reads)

__global__ __launch_bounds__(256)
void k_gemm_dual(const float* __restrict__ X,   // [M,1024]
                 const float* __restrict__ Wl, const float* __restrict__ bl,
                 const float* __restrict__ Wr, const float* __restrict__ br,
                 float* __restrict__ out, int M) {
    __shared__ float xs[BK][XP];   // transposed: [k][row]
    __shared__ float ws[BK][WP];   // transposed: [k][col]
    int tx  = threadIdx.x;
    int gm0 = blockIdx.x * BM;
    int gn0 = blockIdx.y * BN;
    int r = tx >> 4, c = tx & 15;          // 16x16 thread grid, TM=2 TN=4
    int lrow = tx >> 3;                    // 0..31 staging row
    int lkq  = tx & 7;                     // 0..7  float4 chunk along K
    float acc[2][4] = {};

    for (int k0 = 0; k0 < 1024; k0 += BK) {
        {   // stage X tile (transpose)
            int grow = gm0 + lrow;
            float4 v = make_float4(0.f, 0.f, 0.f, 0.f);
            if (grow < M) v = *(const float4*)&X[grow * 1024 + k0 + lkq * 4];
            xs[lkq*4+0][lrow] = v.x;  xs[lkq*4+1][lrow] = v.y;
            xs[lkq*4+2][lrow] = v.z;  xs[lkq*4+3][lrow] = v.w;
        }
        #pragma unroll
        for (int p = 0; p < 2; ++p) {       // stage W tile (2 rows/thread)
            int row = lrow + p * 32;        // 0..63
            int o = gn0 + row;              // 0..2047
            const float* Wp = (o < 1024) ? (Wl + (size_t)o * 1024)
                                         : (Wr + (size_t)(o - 1024) * 1024);
            float4 v = *(const float4*)&Wp[k0 + lkq * 4];
            ws[lkq*4+0][row] = v.x;  ws[lkq*4+1][row] = v.y;
            ws[lkq*4+2][row] = v.z;  ws[lkq*4+3][row] = v.w;
        }
        __syncthreads();
        #pragma unroll
        for (int kk = 0; kk < BK; ++kk) {
            float2 xv = *(const float2*)&xs[kk][r * 2];
            float4 wv = *(const float4*)&ws[kk][c * 4];
            acc[0][0] += xv.x * wv.x;  acc[0][1] += xv.x * wv.y;
            acc[0][2] += xv.x * wv.z;  acc[0][3] += xv.x * wv.w;
            acc[1][0] += xv.y * wv.x;  acc[1][1] += xv.y * wv.y;
            acc[1][2] += xv.y * wv.z;  acc[1][3] += xv.y * wv.w;
        }
        __syncthreads();
    }
    int gn = gn0 + c * 4;
    const float* bp = (gn < 1024) ? (bl + gn) : (br + (gn - 1024));
    float4 bv = *(const float4*)bp;
    #pragma unroll
    for (int mI = 0; mI < 2; ++mI) {
        int gm = gm0 + r * 2 + mI;
        if (gm < M) {
            float4 v = make_float4(acc[mI][0] + bv.x, acc[mI][1] + bv.y,
                                   acc[mI][2] + bv.z, acc[mI][3] + bv.w);
            *(float4*)&out[(size_t)gm * 2048 + gn] = v;
        }
    }
}

// ---------------- fused GATv2 edge phase: online softmax + aggregation ----------------
// one block per (node, head); 4 waves each own an online-softmax state, merged at end
__global__ __launch_bounds__(256)
void k_attn(const float* __restrict__ xlr,    // [N,2048] : [:, :1024]=xl, [:,1024:]=xr
            const float* __restrict__ att,    // [8,128]
            const float* __restrict__ bias,   // [1024]
            const int* __restrict__ offs, const int* __restrict__ srcs,
            float* __restrict__ hout,         // [N,1024]
            int relu_flag) {
    int i = blockIdx.x >> 3;
    int h = blockIdx.x & 7;
    int w = threadIdx.x >> 6;
    int lane = threadIdx.x & 63;
    int cbase = h * CPH + 2 * lane;          // 2 channels per lane

    float2 av = *(const float2*)&att[cbase];
    float2 xr = *(const float2*)&xlr[(size_t)i * 2048 + 1024 + cbase];
    int beg = offs[i], end = offs[i + 1];

    float m = -__builtin_huge_valf(), d = 0.f, ox = 0.f, oy = 0.f;
    for (int e = beg + w; e < end; e += 4) {
        int s = srcs[e];
        float2 xv = *(const float2*)&xlr[(size_t)s * 2048 + cbase];
        float t0 = xv.x + xr.x;  t0 = (t0 >= 0.f) ? t0 : NEG * t0;
        float t1 = xv.y + xr.y;  t1 = (t1 >= 0.f) ? t1 : NEG * t1;
        float p = av.x * t0 + av.y * t1;
        #pragma unroll
        for (int off = 32; off > 0; off >>= 1) p += __shfl_xor(p, off, 64);
        float mn = fmaxf(m, p);
        float f  = __expf(m - mn);      // first iter: exp(-inf)=0
        float ex = __expf(p - mn);
        d  = d  * f + ex;
        ox = ox * f + ex * xv.x;
        oy = oy * f + ex * xv.y;
        m = mn;
    }
    __shared__ float sm[4], sd[4];
    __shared__ float so[4][128];
    if (lane == 0) { sm[w] = m; sd[w] = d; }
    so[w][2*lane] = ox;  so[w][2*lane+1] = oy;
    __syncthreads();
    if (w == 0) {
        float M2 = fmaxf(fmaxf(sm[0], sm[1]), fmaxf(sm[2], sm[3]));
        float D = 0.f, Ox = 0.f, Oy = 0.f;
        #pragma unroll
        for (int ww = 0; ww < 4; ++ww) {
            float f = __expf(sm[ww] - M2);   // idle wave: exp(-inf)=0
            D  += sd[ww] * f;
            Ox += so[ww][2*lane]   * f;
            Oy += so[ww][2*lane+1] * f;
        }
        float inv = 1.f / (D + 1e-16f);
        float r0 = Ox * inv + bias[cbase];
        float r1 = Oy * inv + bias[cbase + 1];
        if (relu_flag) { r0 = fmaxf(r0, 0.f); r1 = fmaxf(r1, 0.f); }
        *(float2*)&hout[(size_t)i * 1024 + cbase] = make_float2(r0, r1);
    }
}

// ---------------- fuse_average + classifier ----------------
__global__ __launch_bounds__(1024)
void k_head(const float* __restrict__ h2,    // [201,1024]
            const float* __restrict__ clfW,  // [2,1024]
            const float* __restrict__ clfb,  // [2]
            float* __restrict__ outp) {
    int c = threadIdx.x;
    float s1 = 0.f, s2 = 0.f;
    #pragma unroll 4
    for (int n = 0; n < 100; ++n)   s1 += h2[(size_t)n * 1024 + c];
    #pragma unroll 4
    for (int n = 100; n < 200; ++n) s2 += h2[(size_t)n * 1024 + c];
    float avg = (s1 * (1.f/100.f) + s2 * (1.f/100.f) + h2[(size_t)200 * 1024 + c]) * (1.f/3.f);
    __shared__ float red[1024];
    red[c] = avg * clfW[c];
    __syncthreads();
    for (int off = 512; off > 0; off >>= 1) {
        if (c < off) red[c] += red[c + off];
        __syncthreads();
    }
    if (c == 0) outp[0] = red[0] + clfb[0];
    __syncthreads();
    red[c] = avg * clfW[1024 + c];
    __syncthreads();
    for (int off = 512; off > 0; off >>= 1) {
        if (c < off) red[c] += red[c + off];
        __syncthreads();
    }
    if (c == 0) outp[1] = red[0] + clfb[1];
}

extern "C" void kernel_launch(void* const* d_in, const int* in_sizes, int n_in,
                              void* d_out, int out_size, void* d_ws, size_t ws_size,
                              hipStream_t stream) {
    const float* x     = (const float*)d_in[0];
    const int*   eids  = (const int*)d_in[1];
    const float* W1l   = (const float*)d_in[2];
    const float* b1l   = (const float*)d_in[3];
    const float* W1r   = (const float*)d_in[4];
    const float* b1r   = (const float*)d_in[5];
    const float* att1  = (const float*)d_in[6];
    const float* bias1 = (const float*)d_in[7];
    const float* W2l   = (const float*)d_in[8];
    const float* b2l   = (const float*)d_in[9];
    const float* W2r   = (const float*)d_in[10];
    const float* b2r   = (const float*)d_in[11];
    const float* att2  = (const float*)d_in[12];
    const float* bias2 = (const float*)d_in[13];
    const float* clfW  = (const float*)d_in[14];
    const float* clfb  = (const float*)d_in[15];
    float* outp = (float*)d_out;

    int N = in_sizes[0] / 1024;   // 201
    int E = in_sizes[1] / 2;      // 40200
    int tot = E + N;              // with self loops

    char* ws = (char*)d_ws;
    int* counts = (int*)ws;  ws += 1024;
    int* offs   = (int*)ws;  ws += 1024;
    int* cursor = (int*)ws;  ws += 1024;
    int* srcs   = (int*)ws;  ws += ((size_t)(tot * 4 + 255) / 256) * 256;
    float* xlr1 = (float*)ws;  ws += (size_t)N * 2048 * 4;
    float* h1   = (float*)ws;  ws += (size_t)N * 1024 * 4;
    float* xlr2 = (float*)ws;  ws += (size_t)N * 2048 * 4;
    float* h2   = (float*)ws;  ws += (size_t)N * 1024 * 4;

    const int* srcA = eids;
    const int* dstA = eids + E;

    k_zero   <<<1, 256, 0, stream>>>(counts, 256);
    k_count  <<<(tot + 255) / 256, 256, 0, stream>>>(dstA, E, N, counts);
    k_scan   <<<1, 256, 0, stream>>>(counts, offs, cursor, N);
    k_scatter<<<(tot + 255) / 256, 256, 0, stream>>>(srcA, dstA, E, N, cursor, srcs);

    dim3 gg((N + BM - 1) / BM, 2048 / BN);
    k_gemm_dual<<<gg, 256, 0, stream>>>(x,  W1l, b1l, W1r, b1r, xlr1, N);
    k_attn     <<<N * HEADS, 256, 0, stream>>>(xlr1, att1, bias1, offs, srcs, h1, 1);
    k_gemm_dual<<<gg, 256, 0, stream>>>(h1, W2l, b2l, W2r, b2r, xlr2, N);
    k_attn     <<<N * HEADS, 256, 0, stream>>>(xlr2, att2, bias2, offs, srcs, h2, 0);
    k_head     <<<1, 1024, 0, stream>>>(h2, clfW, clfb, outp);
}

// Round 5
// 296.039 us; speedup vs baseline: 1.0729x; 1.0729x over previous
//
#include <hip/hip_runtime.h>
#include <hip/hip_bf16.h>

#define HEADS 8
#define NEG   0.2f
#define MPAD  208   // 13 * 16
#define NT    13    // M-tiles of 16

typedef __attribute__((ext_vector_type(8))) short short8v;
typedef __attribute__((ext_vector_type(4))) float float4v;

static __device__ __forceinline__ unsigned short f2bf(float f) {
    unsigned int u = __float_as_uint(f);
    u += 0x7FFF + ((u >> 16) & 1);          // RNE
    return (unsigned short)(u >> 16);
}
static __device__ __forceinline__ float bf2f(unsigned short h) {
    return __uint_as_float(((unsigned int)h) << 16);
}

// ---------------- CSR build (counting sort by dst) ----------------
__global__ void k_zero(int* p, int n) {
    int i = blockIdx.x * blockDim.x + threadIdx.x;
    if (i < n) p[i] = 0;
}

__global__ void k_count(const int* __restrict__ dst, int E, int N, int* counts) {
    int e = blockIdx.x * blockDim.x + threadIdx.x;
    if (e < E + N) {
        int d = (e < E) ? dst[e] : (e - E);   // self-loops appended
        atomicAdd(&counts[d], 1);
    }
}

__global__ void k_scan(const int* __restrict__ counts, int* offs, int* cursor, int N) {
    __shared__ int buf[256];
    int t = threadIdx.x;
    int v = (t < N) ? counts[t] : 0;
    buf[t] = v;
    __syncthreads();
    for (int off = 1; off < 256; off <<= 1) {
        int add = (t >= off) ? buf[t - off] : 0;
        __syncthreads();
        buf[t] += add;
        __syncthreads();
    }
    if (t == 0) offs[0] = 0;
    if (t < N) {
        offs[t + 1] = buf[t];
        cursor[t]   = buf[t] - v;
    }
}

__global__ void k_scatter(const int* __restrict__ srcA, const int* __restrict__ dstA,
                          int E, int N, int* cursor, int* __restrict__ srcs) {
    int e = blockIdx.x * blockDim.x + threadIdx.x;
    if (e < E + N) {
        int d = (e < E) ? dstA[e] : (e - E);
        int s = (e < E) ? srcA[e] : (e - E);
        int pos = atomicAdd(&cursor[d], 1);
        srcs[pos] = s;
    }
}

// ---------------- x (fp32) -> bf16 hi/lo planes [2][208][1024], zero-pad rows 201..207 ----
__global__ __launch_bounds__(256)
void k_convx(const float* __restrict__ x, unsigned short* __restrict__ xpl) {
    int row = blockIdx.x;        // 0..207
    int tx  = threadIdx.x;       // 4 floats each
    float4 v = make_float4(0.f, 0.f, 0.f, 0.f);
    if (row < 201) v = *(const float4*)&x[row * 1024 + tx * 4];
    ushort4 hi, lo;
    hi.x = f2bf(v.x); lo.x = f2bf(v.x - bf2f(hi.x));
    hi.y = f2bf(v.y); lo.y = f2bf(v.y - bf2f(hi.y));
    hi.z = f2bf(v.z); lo.z = f2bf(v.z - bf2f(hi.z));
    hi.w = f2bf(v.w); lo.w = f2bf(v.w - bf2f(hi.w));
    *(ushort4*)&xpl[row * 1024 + tx * 4]               = hi;
    *(ushort4*)&xpl[(MPAD + row) * 1024 + tx * 4]      = lo;
}

// zero rows 201..207 of a plane pair (attn writes only 201 rows; ws is poisoned)
__global__ void k_zeropad(unsigned short* __restrict__ pl) {
    int t = blockIdx.x * blockDim.x + threadIdx.x;  // 2*7*1024 = 14336
    if (t < 14336) {
        int p = t / 7168, rem = t % 7168;
        pl[(p * MPAD + 201) * 1024 + rem] = 0;
    }
}

// ---------------- MFMA split-bf16 dual GEMM, W-stationary ----------------
// C[201,2048] = A[201,1024] @ [Wl;Wr]^T + b.  A given as bf16 hi/lo planes.
// 128 blocks: block b owns cols [16b,16b+16); loops all 13 M-tiles; W read ONCE.
__global__ __launch_bounds__(256)
void k_gemm_mfma(const unsigned short* __restrict__ Apl,  // [2][208][1024]
                 const float* __restrict__ Wl, const float* __restrict__ bl,
                 const float* __restrict__ Wr, const float* __restrict__ br,
                 float* __restrict__ out) {               // [201][2048]
    __shared__ short lA[2 * MPAD * 40];   // [plane][row][40] halfs (pad: 2-way banks only)
    __shared__ short lB[2 * 16 * 40];

    int tx = threadIdx.x;
    int b  = blockIdx.x;
    int wv = tx >> 6, lane = tx & 63;
    int colpan = (b & 63) * 16;
    const float* Wbase = (b < 64) ? Wl : Wr;

    // precompute staging offsets (7 X-segments/thread, 1 W float4 for tx<128)
    int goffX[7], loffX[7];
    #pragma unroll
    for (int j = 0; j < 7; ++j) {
        int idx = tx + 256 * j;          // 0..1791, valid < 1664
        int p = (idx >= 832);
        int rem = idx - p * 832;
        int r = rem >> 2, seg = rem & 3;
        goffX[j] = (p * MPAD + r) * 1024 + seg * 8;
        loffX[j] = (p * MPAD + r) * 40   + seg * 8;
    }
    int wcol = tx >> 3, wseg = tx & 7;   // for tx<128
    size_t goffW = (size_t)(colpan + wcol) * 1024 + wseg * 4;

    short8v xreg[7];
    float4  wreg;

    auto loadChunk = [&](int k0) {
        #pragma unroll
        for (int j = 0; j < 6; ++j)
            xreg[j] = *(const short8v*)&Apl[goffX[j] + k0];
        if (tx < 128) {
            xreg[6] = *(const short8v*)&Apl[goffX[6] + k0];
            wreg    = *(const float4*)&Wbase[goffW + k0];
        }
    };
    auto storeChunk = [&]() {
        #pragma unroll
        for (int j = 0; j < 6; ++j)
            *(short8v*)&lA[loffX[j]] = xreg[j];
        if (tx < 128) {
            *(short8v*)&lA[loffX[6]] = xreg[6];
            ushort4 hi, lo;
            hi.x = f2bf(wreg.x); lo.x = f2bf(wreg.x - bf2f(hi.x));
            hi.y = f2bf(wreg.y); lo.y = f2bf(wreg.y - bf2f(hi.y));
            hi.z = f2bf(wreg.z); lo.z = f2bf(wreg.z - bf2f(hi.z));
            hi.w = f2bf(wreg.w); lo.w = f2bf(wreg.w - bf2f(hi.w));
            *(ushort4*)&lB[wcol * 40 + wseg * 4]        = hi;
            *(ushort4*)&lB[(16 + wcol) * 40 + wseg * 4] = lo;
        }
    };

    float4v acc[4] = {};
    int row16 = lane & 15;
    int k8    = (lane >> 4) * 8;

    loadChunk(0);
    for (int c = 0; c < 32; ++c) {
        __syncthreads();                  // LDS consumers of prev chunk done
        storeChunk();
        __syncthreads();                  // LDS ready
        if (c < 31) loadChunk((c + 1) * 32);   // overlap next loads with MFMA
        short8v bh  = *(const short8v*)&lB[(lane & 15) * 40 + k8];
        short8v blo = *(const short8v*)&lB[(16 + (lane & 15)) * 40 + k8];
        #pragma unroll
        for (int i = 0; i < 4; ++i) {
            int t = wv + 4 * i;
            if (t < NT) {
                short8v ah = *(const short8v*)&lA[(t * 16 + row16) * 40 + k8];
                short8v al = *(const short8v*)&lA[(MPAD + t * 16 + row16) * 40 + k8];
                acc[i] = __builtin_amdgcn_mfma_f32_16x16x32_bf16(ah, bh,  acc[i], 0, 0, 0);
                acc[i] = __builtin_amdgcn_mfma_f32_16x16x32_bf16(al, bh,  acc[i], 0, 0, 0);
                acc[i] = __builtin_amdgcn_mfma_f32_16x16x32_bf16(ah, blo, acc[i], 0, 0, 0);
            }
        }
    }

    int colg = b * 16 + (lane & 15);
    float bias_val = ((b < 64) ? bl : br)[colpan + (lane & 15)];
    #pragma unroll
    for (int i = 0; i < 4; ++i) {
        int t = wv + 4 * i;
        if (t < NT) {
            int rowb = t * 16 + (lane >> 4) * 4;
            #pragma unroll
            for (int j = 0; j < 4; ++j) {
                int row = rowb + j;
                if (row < 201) out[(size_t)row * 2048 + colg] = acc[i][j] + bias_val;
            }
        }
    }
}

// ---------------- fused GATv2 edge phase: online softmax + aggregation ----------------
// prefetched, 2 edges/iter; mode=1: relu + emit bf16 hi/lo planes; mode=0: fp32 out
__global__ __launch_bounds__(256)
void k_attn(const float* __restrict__ xlr,    // [201,2048]: [:, :1024]=xl, [:,1024:]=xr
            const float* __restrict__ att, const float* __restrict__ bias,
            const int* __restrict__ offs, const int* __restrict__ srcs,
            float* __restrict__ foutp, unsigned short* __restrict__ poutp, int mode) {
    int i = blockIdx.x >> 3;
    int h = blockIdx.x & 7;
    int w = threadIdx.x >> 6;
    int lane = threadIdx.x & 63;
    int cbase = h * 128 + 2 * lane;

    float2 av = *(const float2*)&att[cbase];
    float2 xr = *(const float2*)&xlr[(size_t)i * 2048 + 1024 + cbase];
    int beg = offs[i], end = offs[i + 1];

    float m = -__builtin_huge_valf(), d = 0.f, ox = 0.f, oy = 0.f;
    int e0 = beg + w * 2;
    float2 xA0 = make_float2(0.f, 0.f), xA1 = make_float2(0.f, 0.f);
    bool vA1 = (e0 + 1 < end);
    if (e0 < end) xA0 = *(const float2*)&xlr[(size_t)srcs[e0] * 2048 + cbase];
    if (vA1)      xA1 = *(const float2*)&xlr[(size_t)srcs[e0 + 1] * 2048 + cbase];

    for (int e = e0; e < end; e += 8) {
        int en = e + 8;
        float2 xB0 = make_float2(0.f, 0.f), xB1 = make_float2(0.f, 0.f);
        bool vB1 = (en + 1 < end);
        if (en < end) xB0 = *(const float2*)&xlr[(size_t)srcs[en] * 2048 + cbase];
        if (vB1)      xB1 = *(const float2*)&xlr[(size_t)srcs[en + 1] * 2048 + cbase];

        float t0 = xA0.x + xr.x; t0 = (t0 >= 0.f) ? t0 : NEG * t0;
        float t1 = xA0.y + xr.y; t1 = (t1 >= 0.f) ? t1 : NEG * t1;
        float p0 = av.x * t0 + av.y * t1;
        float u0 = xA1.x + xr.x; u0 = (u0 >= 0.f) ? u0 : NEG * u0;
        float u1 = xA1.y + xr.y; u1 = (u1 >= 0.f) ? u1 : NEG * u1;
        float p1 = av.x * u0 + av.y * u1;
        #pragma unroll
        for (int off2 = 32; off2 > 0; off2 >>= 1) {
            p0 += __shfl_xor(p0, off2, 64);
            p1 += __shfl_xor(p1, off2, 64);
        }
        if (!vA1) p1 = -__builtin_huge_valf();
        float mn = fmaxf(m, fmaxf(p0, p1));
        float f  = __expf(m - mn);
        float q0 = __expf(p0 - mn);
        float q1 = __expf(p1 - mn);
        d  = d * f  + q0 + q1;
        ox = ox * f + q0 * xA0.x + q1 * xA1.x;
        oy = oy * f + q0 * xA0.y + q1 * xA1.y;
        m = mn;
        xA0 = xB0; xA1 = xB1; vA1 = vB1;
    }

    __shared__ float sm[4], sd[4];
    __shared__ float so[4][128];
    if (lane == 0) { sm[w] = m; sd[w] = d; }
    so[w][2 * lane] = ox; so[w][2 * lane + 1] = oy;
    __syncthreads();
    if (w == 0) {
        float M2 = fmaxf(fmaxf(sm[0], sm[1]), fmaxf(sm[2], sm[3]));
        float D = 0.f, Ox = 0.f, Oy = 0.f;
        #pragma unroll
        for (int ww = 0; ww < 4; ++ww) {
            float f = __expf(sm[ww] - M2);
            D  += sd[ww] * f;
            Ox += so[ww][2 * lane] * f;
            Oy += so[ww][2 * lane + 1] * f;
        }
        float inv = 1.f / (D + 1e-16f);
        float r0 = Ox * inv + bias[cbase];
        float r1 = Oy * inv + bias[cbase + 1];
        if (mode) {
            r0 = fmaxf(r0, 0.f); r1 = fmaxf(r1, 0.f);
            ushort2 hi, lo;
            hi.x = f2bf(r0); lo.x = f2bf(r0 - bf2f(hi.x));
            hi.y = f2bf(r1); lo.y = f2bf(r1 - bf2f(hi.y));
            *(ushort2*)&poutp[(size_t)i * 1024 + cbase]          = hi;
            *(ushort2*)&poutp[(size_t)(MPAD + i) * 1024 + cbase] = lo;
        } else {
            *(float2*)&foutp[(size_t)i * 1024 + cbase] = make_float2(r0, r1);
        }
    }
}

// ---------------- fuse_average + classifier ----------------
__global__ __launch_bounds__(1024)
void k_head(const float* __restrict__ h2, const float* __restrict__ clfW,
            const float* __restrict__ clfb, float* __restrict__ outp) {
    int c = threadIdx.x;
    float s1 = 0.f, s2 = 0.f;
    #pragma unroll 4
    for (int n = 0; n < 100; ++n)   s1 += h2[(size_t)n * 1024 + c];
    #pragma unroll 4
    for (int n = 100; n < 200; ++n) s2 += h2[(size_t)n * 1024 + c];
    float avg = (s1 * 0.01f + s2 * 0.01f + h2[(size_t)200 * 1024 + c]) * (1.f / 3.f);
    __shared__ float red[1024];
    red[c] = avg * clfW[c];
    __syncthreads();
    for (int off = 512; off > 0; off >>= 1) {
        if (c < off) red[c] += red[c + off];
        __syncthreads();
    }
    if (c == 0) outp[0] = red[0] + clfb[0];
    __syncthreads();
    red[c] = avg * clfW[1024 + c];
    __syncthreads();
    for (int off = 512; off > 0; off >>= 1) {
        if (c < off) red[c] += red[c + off];
        __syncthreads();
    }
    if (c == 0) outp[1] = red[0] + clfb[1];
}

extern "C" void kernel_launch(void* const* d_in, const int* in_sizes, int n_in,
                              void* d_out, int out_size, void* d_ws, size_t ws_size,
                              hipStream_t stream) {
    const float* x     = (const float*)d_in[0];
    const int*   eids  = (const int*)d_in[1];
    const float* W1l   = (const float*)d_in[2];
    const float* b1l   = (const float*)d_in[3];
    const float* W1r   = (const float*)d_in[4];
    const float* b1r   = (const float*)d_in[5];
    const float* att1  = (const float*)d_in[6];
    const float* bias1 = (const float*)d_in[7];
    const float* W2l   = (const float*)d_in[8];
    const float* b2l   = (const float*)d_in[9];
    const float* W2r   = (const float*)d_in[10];
    const float* b2r   = (const float*)d_in[11];
    const float* att2  = (const float*)d_in[12];
    const float* bias2 = (const float*)d_in[13];
    const float* clfW  = (const float*)d_in[14];
    const float* clfb  = (const float*)d_in[15];
    float* outp = (float*)d_out;

    int N = in_sizes[0] / 1024;   // 201
    int E = in_sizes[1] / 2;      // 40200
    int tot = E + N;

    char* wsp = (char*)d_ws;
    int* counts = (int*)wsp;  wsp += 1024;
    int* offs   = (int*)wsp;  wsp += 1024;
    int* cursor = (int*)wsp;  wsp += 1024;
    int* srcs   = (int*)wsp;  wsp += ((size_t)(tot * 4 + 255) / 256) * 256;
    unsigned short* xpl = (unsigned short*)wsp;  wsp += 2 * MPAD * 1024 * 2;  // 851968
    unsigned short* hpl = (unsigned short*)wsp;  wsp += 2 * MPAD * 1024 * 2;
    float* xlr1 = (float*)wsp;  wsp += (size_t)201 * 2048 * 4;
    float* xlr2 = (float*)wsp;  wsp += (size_t)201 * 2048 * 4;
    float* h2   = (float*)xpl;   // reuse: xpl dead after gemm1; attn2 writes h2 after

    const int* srcA = eids;
    const int* dstA = eids + E;

    k_zero   <<<1, 256, 0, stream>>>(counts, 256);
    k_count  <<<(tot + 255) / 256, 256, 0, stream>>>(dstA, E, N, counts);
    k_scan   <<<1, 256, 0, stream>>>(counts, offs, cursor, N);
    k_scatter<<<(tot + 255) / 256, 256, 0, stream>>>(srcA, dstA, E, N, cursor, srcs);

    k_convx  <<<MPAD, 256, 0, stream>>>(x, xpl);
    k_zeropad<<<56, 256, 0, stream>>>(hpl);

    k_gemm_mfma<<<128, 256, 0, stream>>>(xpl, W1l, b1l, W1r, b1r, xlr1);
    k_attn     <<<N * HEADS, 256, 0, stream>>>(xlr1, att1, bias1, offs, srcs,
                                               (float*)nullptr, hpl, 1);
    k_gemm_mfma<<<128, 256, 0, stream>>>(hpl, W2l, b2l, W2r, b2r, xlr2);
    k_attn     <<<N * HEADS, 256, 0, stream>>>(xlr2, att2, bias2, offs, srcs,
                                               h2, (unsigned short*)nullptr, 0);
    k_head     <<<1, 1024, 0, stream>>>(h2, clfW, clfb, outp);
}

// Round 7
// 263.912 us; speedup vs baseline: 1.2035x; 1.1217x over previous
//
#include <hip/hip_runtime.h>
#include <hip/hip_bf16.h>

#define HEADS 8
#define NEG   0.2f
#define MPAD  208   // plane row count (13*16)
#define HROWS 112   // rows per M-half in gemm

typedef __attribute__((ext_vector_type(8))) short short8v;
typedef __attribute__((ext_vector_type(4))) float float4v;

static __device__ __forceinline__ unsigned short f2bf(float f) {
    unsigned int u = __float_as_uint(f);
    u += 0x7FFF + ((u >> 16) & 1);          // RNE
    return (unsigned short)(u >> 16);
}
static __device__ __forceinline__ float bf2f(unsigned short h) {
    return __uint_as_float(((unsigned int)h) << 16);
}

// ---------------- CSR build (counting sort by dst) ----------------
__global__ void k_zero(int* p, int n) {
    int i = blockIdx.x * blockDim.x + threadIdx.x;
    if (i < n) p[i] = 0;
}

__global__ void k_count(const int* __restrict__ dst, int E, int N, int* counts) {
    int e = blockIdx.x * blockDim.x + threadIdx.x;
    if (e < E + N) {
        int d = (e < E) ? dst[e] : (e - E);   // self-loops appended
        atomicAdd(&counts[d], 1);
    }
}

__global__ void k_scan(const int* __restrict__ counts, int* offs, int* cursor, int N) {
    __shared__ int buf[256];
    int t = threadIdx.x;
    int v = (t < N) ? counts[t] : 0;
    buf[t] = v;
    __syncthreads();
    for (int off = 1; off < 256; off <<= 1) {
        int add = (t >= off) ? buf[t - off] : 0;
        __syncthreads();
        buf[t] += add;
        __syncthreads();
    }
    if (t == 0) offs[0] = 0;
    if (t < N) {
        offs[t + 1] = buf[t];
        cursor[t]   = buf[t] - v;
    }
}

__global__ void k_scatter(const int* __restrict__ srcA, const int* __restrict__ dstA,
                          int E, int N, int* cursor, int* __restrict__ srcs) {
    int e = blockIdx.x * blockDim.x + threadIdx.x;
    if (e < E + N) {
        int d = (e < E) ? dstA[e] : (e - E);
        int s = (e < E) ? srcA[e] : (e - E);
        int pos = atomicAdd(&cursor[d], 1);
        srcs[pos] = s;
    }
}

// ---------------- MFMA split-bf16 dual GEMM, W-stationary, fused fp32->bf16hi/lo ----
// C[201,2048] = A[201,1024] @ [Wl;Wr]^T + b.
// MODE 0: A = fp32 x [201][1024] (converted to hi/lo during staging)
// MODE 1: A = bf16 planes [2][MPAD][1024] (rows >=201 garbage -> guarded to 0)
// 256 blocks = 128 col-panels x 2 M-halves (rows 0-111 / 112-207). W read ~once.
template<int MODE>
__global__ __launch_bounds__(256)
void k_gemm_mfma(const float* __restrict__ Xf, const unsigned short* __restrict__ Apl,
                 const float* __restrict__ Wl, const float* __restrict__ bl,
                 const float* __restrict__ Wr, const float* __restrict__ br,
                 float* __restrict__ out) {               // [201][2048]
    __shared__ short lA[2 * HROWS * 40];   // [plane][row][40] halfs
    __shared__ short lB[2 * 16 * 40];

    int tx = threadIdx.x;
    int panel = blockIdx.x >> 1;
    int half  = blockIdx.x & 1;
    int row0  = half * HROWS;
    int ntiles = half ? 6 : 7;             // half1 covers rows 112..207 (6 tiles)
    int wv = tx >> 6, lane = tx & 63;
    int colpan = (panel & 63) * 16;
    const float* Wbase = (panel < 64) ? Wl : Wr;

    // staging decomposition: 896 segments, j=0..2 always valid, j=3 iff tx<128
    int gX[4], lX[4], rowv[4];
    #pragma unroll
    for (int j = 0; j < 4; ++j) {
        int idx = tx + 256 * j;            // < 896 valid
        if (MODE == 0) {
            int r = idx >> 3, seg = idx & 7;           // float4 seg
            rowv[j] = row0 + r;
            gX[j] = (row0 + r) * 1024 + seg * 4;
            lX[j] = r * 40 + seg * 4;
        } else {
            int p = (idx >= 448);
            int rem = idx - p * 448;
            int r = rem >> 2, seg = rem & 3;           // short8 seg
            rowv[j] = row0 + r;
            gX[j] = (p * MPAD + row0 + r) * 1024 + seg * 8;
            lX[j] = p * (HROWS * 40) + r * 40 + seg * 8;
        }
    }
    int wcol = tx >> 3, wseg = tx & 7;     // for tx<128
    size_t goffW = (size_t)(colpan + wcol) * 1024 + wseg * 4;

    float4  af[4];      // MODE 0 staging regs
    short8v ap[4];      // MODE 1 staging regs
    float4  wreg;

    auto loadChunk = [&](int k0) {
        #pragma unroll
        for (int j = 0; j < 3; ++j) {
            if (MODE == 0) {
                af[j] = (rowv[j] < 201) ? *(const float4*)&Xf[gX[j] + k0]
                                        : make_float4(0.f, 0.f, 0.f, 0.f);
            } else {
                ap[j] = (rowv[j] < 201) ? *(const short8v*)&Apl[gX[j] + k0]
                                        : short8v{0,0,0,0,0,0,0,0};
            }
        }
        if (tx < 128) {
            if (MODE == 0) {
                af[3] = (rowv[3] < 201) ? *(const float4*)&Xf[gX[3] + k0]
                                        : make_float4(0.f, 0.f, 0.f, 0.f);
            } else {
                ap[3] = (rowv[3] < 201) ? *(const short8v*)&Apl[gX[3] + k0]
                                        : short8v{0,0,0,0,0,0,0,0};
            }
            wreg = *(const float4*)&Wbase[goffW + k0];
        }
    };
    auto storeSeg = [&](int j) {
        if (MODE == 0) {
            ushort4 hi, lo;
            hi.x = f2bf(af[j].x); lo.x = f2bf(af[j].x - bf2f(hi.x));
            hi.y = f2bf(af[j].y); lo.y = f2bf(af[j].y - bf2f(hi.y));
            hi.z = f2bf(af[j].z); lo.z = f2bf(af[j].z - bf2f(hi.z));
            hi.w = f2bf(af[j].w); lo.w = f2bf(af[j].w - bf2f(hi.w));
            *(ushort4*)&lA[lX[j]]              = hi;
            *(ushort4*)&lA[HROWS * 40 + lX[j]] = lo;
        } else {
            *(short8v*)&lA[lX[j]] = ap[j];
        }
    };
    auto storeChunk = [&]() {
        #pragma unroll
        for (int j = 0; j < 3; ++j) storeSeg(j);
        if (tx < 128) {
            storeSeg(3);
            ushort4 hi, lo;
            hi.x = f2bf(wreg.x); lo.x = f2bf(wreg.x - bf2f(hi.x));
            hi.y = f2bf(wreg.y); lo.y = f2bf(wreg.y - bf2f(hi.y));
            hi.z = f2bf(wreg.z); lo.z = f2bf(wreg.z - bf2f(hi.z));
            hi.w = f2bf(wreg.w); lo.w = f2bf(wreg.w - bf2f(hi.w));
            *(ushort4*)&lB[wcol * 40 + wseg * 4]        = hi;
            *(ushort4*)&lB[(16 + wcol) * 40 + wseg * 4] = lo;
        }
    };

    float4v acc[2] = {};
    int row16 = lane & 15;
    int k8    = (lane >> 4) * 8;

    loadChunk(0);
    for (int c = 0; c < 32; ++c) {
        __syncthreads();
        storeChunk();
        __syncthreads();
        if (c < 31) loadChunk((c + 1) * 32);
        short8v bh  = *(const short8v*)&lB[row16 * 40 + k8];
        short8v blo = *(const short8v*)&lB[(16 + row16) * 40 + k8];
        #pragma unroll
        for (int i = 0; i < 2; ++i) {
            int t = wv + 4 * i;
            if (t < ntiles) {
                short8v ah = *(const short8v*)&lA[(t * 16 + row16) * 40 + k8];
                short8v al = *(const short8v*)&lA[HROWS * 40 + (t * 16 + row16) * 40 + k8];
                acc[i] = __builtin_amdgcn_mfma_f32_16x16x32_bf16(ah, bh,  acc[i], 0, 0, 0);
                acc[i] = __builtin_amdgcn_mfma_f32_16x16x32_bf16(al, bh,  acc[i], 0, 0, 0);
                acc[i] = __builtin_amdgcn_mfma_f32_16x16x32_bf16(ah, blo, acc[i], 0, 0, 0);
            }
        }
    }

    int colg = panel * 16 + row16;
    float bias_val = ((panel < 64) ? bl : br)[colpan + row16];
    #pragma unroll
    for (int i = 0; i < 2; ++i) {
        int t = wv + 4 * i;
        if (t < ntiles) {
            int rowb = row0 + t * 16 + (lane >> 4) * 4;
            #pragma unroll
            for (int j = 0; j < 4; ++j) {
                int row = rowb + j;
                if (row < 201) out[(size_t)row * 2048 + colg] = acc[i][j] + bias_val;
            }
        }
    }
}

// ---------------- fused GATv2 edge phase: online softmax + aggregation ----------------
// mode=1: relu + emit bf16 hi/lo planes (layer 1)
// mode=0: fused classifier partials (layer 2): part[bid], part[n8+bid]
__global__ __launch_bounds__(256)
void k_attn(const float* __restrict__ xlr,    // [201,2048]: [:, :1024]=xl, [:,1024:]=xr
            const float* __restrict__ att, const float* __restrict__ bias,
            const int* __restrict__ offs, const int* __restrict__ srcs,
            unsigned short* __restrict__ poutp,
            const float* __restrict__ clfW, float* __restrict__ part,
            int n8, int mode) {
    int i = blockIdx.x >> 3;
    int h = blockIdx.x & 7;
    int w = threadIdx.x >> 6;
    int lane = threadIdx.x & 63;
    int cbase = h * 128 + 2 * lane;

    float2 av = *(const float2*)&att[cbase];
    float2 xr = *(const float2*)&xlr[(size_t)i * 2048 + 1024 + cbase];
    int beg = offs[i], end = offs[i + 1];

    float m = -__builtin_huge_valf(), d = 0.f, ox = 0.f, oy = 0.f;
    int e0 = beg + w * 2;
    float2 xA0 = make_float2(0.f, 0.f), xA1 = make_float2(0.f, 0.f);
    bool vA1 = (e0 + 1 < end);
    if (e0 < end) xA0 = *(const float2*)&xlr[(size_t)srcs[e0] * 2048 + cbase];
    if (vA1)      xA1 = *(const float2*)&xlr[(size_t)srcs[e0 + 1] * 2048 + cbase];

    for (int e = e0; e < end; e += 8) {
        int en = e + 8;
        float2 xB0 = make_float2(0.f, 0.f), xB1 = make_float2(0.f, 0.f);
        bool vB1 = (en + 1 < end);
        if (en < end) xB0 = *(const float2*)&xlr[(size_t)srcs[en] * 2048 + cbase];
        if (vB1)      xB1 = *(const float2*)&xlr[(size_t)srcs[en + 1] * 2048 + cbase];

        float t0 = xA0.x + xr.x; t0 = (t0 >= 0.f) ? t0 : NEG * t0;
        float t1 = xA0.y + xr.y; t1 = (t1 >= 0.f) ? t1 : NEG * t1;
        float p0 = av.x * t0 + av.y * t1;
        float u0 = xA1.x + xr.x; u0 = (u0 >= 0.f) ? u0 : NEG * u0;
        float u1 = xA1.y + xr.y; u1 = (u1 >= 0.f) ? u1 : NEG * u1;
        float p1 = av.x * u0 + av.y * u1;
        #pragma unroll
        for (int off2 = 32; off2 > 0; off2 >>= 1) {
            p0 += __shfl_xor(p0, off2, 64);
            p1 += __shfl_xor(p1, off2, 64);
        }
        if (!vA1) p1 = -__builtin_huge_valf();
        float mn = fmaxf(m, fmaxf(p0, p1));
        float f  = __expf(m - mn);
        float q0 = __expf(p0 - mn);
        float q1 = __expf(p1 - mn);
        d  = d * f  + q0 + q1;
        ox = ox * f + q0 * xA0.x + q1 * xA1.x;
        oy = oy * f + q0 * xA0.y + q1 * xA1.y;
        m = mn;
        xA0 = xB0; xA1 = xB1; vA1 = vB1;
    }

    __shared__ float sm[4], sd[4];
    __shared__ float so[4][128];
    if (lane == 0) { sm[w] = m; sd[w] = d; }
    so[w][2 * lane] = ox; so[w][2 * lane + 1] = oy;
    __syncthreads();
    if (w == 0) {
        float M2 = fmaxf(fmaxf(sm[0], sm[1]), fmaxf(sm[2], sm[3]));
        float D = 0.f, Ox = 0.f, Oy = 0.f;
        #pragma unroll
        for (int ww = 0; ww < 4; ++ww) {
            float f = __expf(sm[ww] - M2);
            D  += sd[ww] * f;
            Ox += so[ww][2 * lane] * f;
            Oy += so[ww][2 * lane + 1] * f;
        }
        float inv = 1.f / (D + 1e-16f);
        float r0 = Ox * inv + bias[cbase];
        float r1 = Oy * inv + bias[cbase + 1];
        if (mode) {
            r0 = fmaxf(r0, 0.f); r1 = fmaxf(r1, 0.f);
            ushort2 hi, lo;
            hi.x = f2bf(r0); lo.x = f2bf(r0 - bf2f(hi.x));
            hi.y = f2bf(r1); lo.y = f2bf(r1 - bf2f(hi.y));
            *(ushort2*)&poutp[(size_t)i * 1024 + cbase]          = hi;
            *(ushort2*)&poutp[(size_t)(MPAD + i) * 1024 + cbase] = lo;
        } else {
            // fused classifier partial: this block owns 128 channels of h2 row i
            float2 c0 = *(const float2*)&clfW[cbase];
            float2 c1 = *(const float2*)&clfW[1024 + cbase];
            float s0 = r0 * c0.x + r1 * c0.y;
            float s1 = r0 * c1.x + r1 * c1.y;
            #pragma unroll
            for (int off2 = 32; off2 > 0; off2 >>= 1) {
                s0 += __shfl_xor(s0, off2, 64);
                s1 += __shfl_xor(s1, off2, 64);
            }
            if (lane == 0) {
                float wgt = (i == 200) ? (1.f / 3.f) : (1.f / 300.f);
                part[blockIdx.x]      = wgt * s0;
                part[n8 + blockIdx.x] = wgt * s1;
            }
        }
    }
}

// ---------------- finalize: reduce per-block classifier partials ----------------
__global__ __launch_bounds__(256)
void k_finalize(const float* __restrict__ part, const float* __restrict__ clfb,
                float* __restrict__ outp, int n8) {
    int t = threadIdx.x;
    float s0 = 0.f, s1 = 0.f;
    for (int j = t; j < n8; j += 256) {
        s0 += part[j];
        s1 += part[n8 + j];
    }
    __shared__ float r0[256], r1[256];
    r0[t] = s0; r1[t] = s1;
    __syncthreads();
    for (int off = 128; off > 0; off >>= 1) {
        if (t < off) { r0[t] += r0[t + off]; r1[t] += r1[t + off]; }
        __syncthreads();
    }
    if (t == 0) {
        outp[0] = r0[0] + clfb[0];
        outp[1] = r1[0] + clfb[1];
    }
}

extern "C" void kernel_launch(void* const* d_in, const int* in_sizes, int n_in,
                              void* d_out, int out_size, void* d_ws, size_t ws_size,
                              hipStream_t stream) {
    const float* x     = (const float*)d_in[0];
    const int*   eids  = (const int*)d_in[1];
    const float* W1l   = (const float*)d_in[2];
    const float* b1l   = (const float*)d_in[3];
    const float* W1r   = (const float*)d_in[4];
    const float* b1r   = (const float*)d_in[5];
    const float* att1  = (const float*)d_in[6];
    const float* bias1 = (const float*)d_in[7];
    const float* W2l   = (const float*)d_in[8];
    const float* b2l   = (const float*)d_in[9];
    const float* W2r   = (const float*)d_in[10];
    const float* b2r   = (const float*)d_in[11];
    const float* att2  = (const float*)d_in[12];
    const float* bias2 = (const float*)d_in[13];
    const float* clfW  = (const float*)d_in[14];
    const float* clfb  = (const float*)d_in[15];
    float* outp = (float*)d_out;

    int N = in_sizes[0] / 1024;   // 201
    int E = in_sizes[1] / 2;      // 40200
    int tot = E + N;
    int n8 = N * HEADS;           // 1608

    char* wsp = (char*)d_ws;
    int* counts = (int*)wsp;  wsp += 1024;
    int* offs   = (int*)wsp;  wsp += 1024;
    int* cursor = (int*)wsp;  wsp += 1024;
    int* srcs   = (int*)wsp;  wsp += ((size_t)(tot * 4 + 255) / 256) * 256;
    unsigned short* hpl = (unsigned short*)wsp;  wsp += 2 * MPAD * 1024 * 2;  // bf16 planes
    float* xlr1 = (float*)wsp;  wsp += (size_t)201 * 2048 * 4;
    float* xlr2 = (float*)wsp;  wsp += (size_t)201 * 2048 * 4;
    float* part = (float*)wsp;  wsp += (size_t)2 * n8 * 4;

    const int* srcA = eids;
    const int* dstA = eids + E;

    k_zero   <<<1, 256, 0, stream>>>(counts, 256);
    k_count  <<<(tot + 255) / 256, 256, 0, stream>>>(dstA, E, N, counts);
    k_scan   <<<1, 256, 0, stream>>>(counts, offs, cursor, N);
    k_scatter<<<(tot + 255) / 256, 256, 0, stream>>>(srcA, dstA, E, N, cursor, srcs);

    k_gemm_mfma<0><<<256, 256, 0, stream>>>(x, (const unsigned short*)nullptr,
                                            W1l, b1l, W1r, b1r, xlr1);
    k_attn<<<n8, 256, 0, stream>>>(xlr1, att1, bias1, offs, srcs,
                                   hpl, (const float*)nullptr, (float*)nullptr, n8, 1);
    k_gemm_mfma<1><<<256, 256, 0, stream>>>((const float*)nullptr, hpl,
                                            W2l, b2l, W2r, b2r, xlr2);
    k_attn<<<n8, 256, 0, stream>>>(xlr2, att2, bias2, offs, srcs,
                                   (unsigned short*)nullptr, clfW, part, n8, 0);
    k_finalize<<<1, 256, 0, stream>>>(part, clfb, outp, n8);
}

// Round 8
// 261.140 us; speedup vs baseline: 1.2163x; 1.0106x over previous
//
#include <hip/hip_runtime.h>
#include <hip/hip_bf16.h>

#define HEADS 8
#define NEG   0.2f
#define MPAD  208   // plane row count (13*16)
#define HROWS 112   // rows per M-half in gemm

typedef __attribute__((ext_vector_type(8))) short short8v;
typedef __attribute__((ext_vector_type(4))) float float4v;

static __device__ __forceinline__ unsigned short f2bf(float f) {
    unsigned int u = __float_as_uint(f);
    u += 0x7FFF + ((u >> 16) & 1);          // RNE
    return (unsigned short)(u >> 16);
}
static __device__ __forceinline__ float bf2f(unsigned short h) {
    return __uint_as_float(((unsigned int)h) << 16);
}

// ---------------- CSR: count + scan in one block; also init outp with clfb ----
__global__ __launch_bounds__(1024)
void k_countscan(const int* __restrict__ dstA, int E, int N,
                 int* __restrict__ offs, int* __restrict__ cursor,
                 const float* __restrict__ clfb, float* __restrict__ outp) {
    __shared__ int cnt[256];
    __shared__ int buf[256];
    int t = threadIdx.x;
    if (t < 256) cnt[t] = 0;
    __syncthreads();
    for (int e = t; e < E + N; e += 1024) {
        int d = (e < E) ? dstA[e] : (e - E);   // self-loops appended
        atomicAdd(&cnt[d], 1);
    }
    __syncthreads();
    if (t < 256) buf[t] = cnt[t];
    __syncthreads();
    for (int off = 1; off < 256; off <<= 1) {
        int add = (t >= off && t < 256) ? buf[t - off] : 0;
        __syncthreads();
        if (t < 256) buf[t] += add;
        __syncthreads();
    }
    if (t == 0) { offs[0] = 0; outp[0] = clfb[0]; outp[1] = clfb[1]; }
    if (t < N) {
        offs[t + 1] = buf[t];
        cursor[t]   = buf[t] - cnt[t];   // exclusive prefix
    }
}

__global__ void k_scatter(const int* __restrict__ srcA, const int* __restrict__ dstA,
                          int E, int N, int* cursor, int* __restrict__ srcs) {
    int e = blockIdx.x * blockDim.x + threadIdx.x;
    if (e < E + N) {
        int d = (e < E) ? dstA[e] : (e - E);
        int s = (e < E) ? srcA[e] : (e - E);
        int pos = atomicAdd(&cursor[d], 1);
        srcs[pos] = s;
    }
}

// ---------------- MFMA split-bf16 dual GEMM, W-stationary, fused fp32->bf16hi/lo ----
// (unchanged from round 7 — verified passing)
template<int MODE>
__global__ __launch_bounds__(256)
void k_gemm_mfma(const float* __restrict__ Xf, const unsigned short* __restrict__ Apl,
                 const float* __restrict__ Wl, const float* __restrict__ bl,
                 const float* __restrict__ Wr, const float* __restrict__ br,
                 float* __restrict__ out) {               // [201][2048]
    __shared__ short lA[2 * HROWS * 40];
    __shared__ short lB[2 * 16 * 40];

    int tx = threadIdx.x;
    int panel = blockIdx.x >> 1;
    int half  = blockIdx.x & 1;
    int row0  = half * HROWS;
    int ntiles = half ? 6 : 7;
    int wv = tx >> 6, lane = tx & 63;
    int colpan = (panel & 63) * 16;
    const float* Wbase = (panel < 64) ? Wl : Wr;

    int gX[4], lX[4], rowv[4];
    #pragma unroll
    for (int j = 0; j < 4; ++j) {
        int idx = tx + 256 * j;
        if (MODE == 0) {
            int r = idx >> 3, seg = idx & 7;
            rowv[j] = row0 + r;
            gX[j] = (row0 + r) * 1024 + seg * 4;
            lX[j] = r * 40 + seg * 4;
        } else {
            int p = (idx >= 448);
            int rem = idx - p * 448;
            int r = rem >> 2, seg = rem & 3;
            rowv[j] = row0 + r;
            gX[j] = (p * MPAD + row0 + r) * 1024 + seg * 8;
            lX[j] = p * (HROWS * 40) + r * 40 + seg * 8;
        }
    }
    int wcol = tx >> 3, wseg = tx & 7;
    size_t goffW = (size_t)(colpan + wcol) * 1024 + wseg * 4;

    float4  af[4];
    short8v ap[4];
    float4  wreg;

    auto loadChunk = [&](int k0) {
        #pragma unroll
        for (int j = 0; j < 3; ++j) {
            if (MODE == 0) {
                af[j] = (rowv[j] < 201) ? *(const float4*)&Xf[gX[j] + k0]
                                        : make_float4(0.f, 0.f, 0.f, 0.f);
            } else {
                ap[j] = (rowv[j] < 201) ? *(const short8v*)&Apl[gX[j] + k0]
                                        : short8v{0,0,0,0,0,0,0,0};
            }
        }
        if (tx < 128) {
            if (MODE == 0) {
                af[3] = (rowv[3] < 201) ? *(const float4*)&Xf[gX[3] + k0]
                                        : make_float4(0.f, 0.f, 0.f, 0.f);
            } else {
                ap[3] = (rowv[3] < 201) ? *(const short8v*)&Apl[gX[3] + k0]
                                        : short8v{0,0,0,0,0,0,0,0};
            }
            wreg = *(const float4*)&Wbase[goffW + k0];
        }
    };
    auto storeSeg = [&](int j) {
        if (MODE == 0) {
            ushort4 hi, lo;
            hi.x = f2bf(af[j].x); lo.x = f2bf(af[j].x - bf2f(hi.x));
            hi.y = f2bf(af[j].y); lo.y = f2bf(af[j].y - bf2f(hi.y));
            hi.z = f2bf(af[j].z); lo.z = f2bf(af[j].z - bf2f(hi.z));
            hi.w = f2bf(af[j].w); lo.w = f2bf(af[j].w - bf2f(hi.w));
            *(ushort4*)&lA[lX[j]]              = hi;
            *(ushort4*)&lA[HROWS * 40 + lX[j]] = lo;
        } else {
            *(short8v*)&lA[lX[j]] = ap[j];
        }
    };
    auto storeChunk = [&]() {
        #pragma unroll
        for (int j = 0; j < 3; ++j) storeSeg(j);
        if (tx < 128) {
            storeSeg(3);
            ushort4 hi, lo;
            hi.x = f2bf(wreg.x); lo.x = f2bf(wreg.x - bf2f(hi.x));
            hi.y = f2bf(wreg.y); lo.y = f2bf(wreg.y - bf2f(hi.y));
            hi.z = f2bf(wreg.z); lo.z = f2bf(wreg.z - bf2f(hi.z));
            hi.w = f2bf(wreg.w); lo.w = f2bf(wreg.w - bf2f(hi.w));
            *(ushort4*)&lB[wcol * 40 + wseg * 4]        = hi;
            *(ushort4*)&lB[(16 + wcol) * 40 + wseg * 4] = lo;
        }
    };

    float4v acc[2] = {};
    int row16 = lane & 15;
    int k8    = (lane >> 4) * 8;

    loadChunk(0);
    for (int c = 0; c < 32; ++c) {
        __syncthreads();
        storeChunk();
        __syncthreads();
        if (c < 31) loadChunk((c + 1) * 32);
        short8v bh  = *(const short8v*)&lB[row16 * 40 + k8];
        short8v blo = *(const short8v*)&lB[(16 + row16) * 40 + k8];
        #pragma unroll
        for (int i = 0; i < 2; ++i) {
            int t = wv + 4 * i;
            if (t < ntiles) {
                short8v ah = *(const short8v*)&lA[(t * 16 + row16) * 40 + k8];
                short8v al = *(const short8v*)&lA[HROWS * 40 + (t * 16 + row16) * 40 + k8];
                acc[i] = __builtin_amdgcn_mfma_f32_16x16x32_bf16(ah, bh,  acc[i], 0, 0, 0);
                acc[i] = __builtin_amdgcn_mfma_f32_16x16x32_bf16(al, bh,  acc[i], 0, 0, 0);
                acc[i] = __builtin_amdgcn_mfma_f32_16x16x32_bf16(ah, blo, acc[i], 0, 0, 0);
            }
        }
    }

    int colg = panel * 16 + row16;
    float bias_val = ((panel < 64) ? bl : br)[colpan + row16];
    #pragma unroll
    for (int i = 0; i < 2; ++i) {
        int t = wv + 4 * i;
        if (t < ntiles) {
            int rowb = row0 + t * 16 + (lane >> 4) * 4;
            #pragma unroll
            for (int j = 0; j < 4; ++j) {
                int row = rowb + j;
                if (row < 201) out[(size_t)row * 2048 + colg] = acc[i][j] + bias_val;
            }
        }
    }
}

// ---------------- fused GATv2 edge phase, group-of-8 edge parallelism ----------------
// Each 8-lane group owns one edge (16 ch/lane); 8 edges per wave per batch;
// one online-softmax rescale per batch. Exact (batch online softmax).
// mode=1: relu + emit bf16 hi/lo planes.  mode=0: classifier atomicAdd to outp.
__global__ __launch_bounds__(256)
void k_attn(const float* __restrict__ xlr,    // [201,2048]: [:, :1024]=xl, [:,1024:]=xr
            const float* __restrict__ att, const float* __restrict__ bias,
            const int* __restrict__ offs, const int* __restrict__ srcs,
            unsigned short* __restrict__ poutp,
            const float* __restrict__ clfW, float* __restrict__ outp, int mode) {
    int i = blockIdx.x >> 3;
    int h = blockIdx.x & 7;
    int w = threadIdx.x >> 6;
    int lane = threadIdx.x & 63;
    int g  = lane >> 3;              // edge slot 0..7
    int c8 = (lane & 7) * 16;        // 16 channels per lane
    size_t hb = (size_t)h * 128 + c8;

    float4 xr[4], at[4];
    #pragma unroll
    for (int k = 0; k < 4; ++k) {
        xr[k] = *(const float4*)&xlr[(size_t)i * 2048 + 1024 + hb + k * 4];
        at[k] = *(const float4*)&att[hb + k * 4];
    }

    int beg = offs[i], end = offs[i + 1];
    float m = -__builtin_huge_valf(), d = 0.f;
    float4 acc[4] = {};

    for (int base = beg + w * 8; base < end; base += 32) {
        int e = base + g;
        bool val = (e < end);
        int s = srcs[val ? e : base];
        const float* xp = &xlr[(size_t)s * 2048 + hb];
        float4 xv[4];
        #pragma unroll
        for (int k = 0; k < 4; ++k) xv[k] = *(const float4*)&xp[k * 4];

        float sc = 0.f;
        #pragma unroll
        for (int k = 0; k < 4; ++k) {
            float t0, l0;
            t0 = xv[k].x + xr[k].x; l0 = fmaxf(t0, 0.f) + NEG * fminf(t0, 0.f); sc = fmaf(at[k].x, l0, sc);
            t0 = xv[k].y + xr[k].y; l0 = fmaxf(t0, 0.f) + NEG * fminf(t0, 0.f); sc = fmaf(at[k].y, l0, sc);
            t0 = xv[k].z + xr[k].z; l0 = fmaxf(t0, 0.f) + NEG * fminf(t0, 0.f); sc = fmaf(at[k].z, l0, sc);
            t0 = xv[k].w + xr[k].w; l0 = fmaxf(t0, 0.f) + NEG * fminf(t0, 0.f); sc = fmaf(at[k].w, l0, sc);
        }
        // within-group dot reduce (stays inside 8-lane group)
        sc += __shfl_xor(sc, 1, 64);
        sc += __shfl_xor(sc, 2, 64);
        sc += __shfl_xor(sc, 4, 64);
        if (!val) sc = -__builtin_huge_valf();
        // batch max across groups -> wave-uniform
        float bm = sc;
        bm = fmaxf(bm, __shfl_xor(bm, 8, 64));
        bm = fmaxf(bm, __shfl_xor(bm, 16, 64));
        bm = fmaxf(bm, __shfl_xor(bm, 32, 64));
        float mn = fmaxf(m, bm);
        float f  = __expf(m - mn);            // first batch: exp(-inf)=0
        float q  = val ? __expf(sc - mn) : 0.f;
        d = d * f + (((lane & 7) == 0) ? q : 0.f);
        #pragma unroll
        for (int k = 0; k < 4; ++k) {
            acc[k].x = fmaf(acc[k].x, f, q * xv[k].x);
            acc[k].y = fmaf(acc[k].y, f, q * xv[k].y);
            acc[k].z = fmaf(acc[k].z, f, q * xv[k].z);
            acc[k].w = fmaf(acc[k].w, f, q * xv[k].w);
        }
        m = mn;
    }

    // cross-group sum of acc (once per wave)
    #pragma unroll
    for (int hop = 8; hop <= 32; hop <<= 1) {
        #pragma unroll
        for (int k = 0; k < 4; ++k) {
            acc[k].x += __shfl_xor(acc[k].x, hop, 64);
            acc[k].y += __shfl_xor(acc[k].y, hop, 64);
            acc[k].z += __shfl_xor(acc[k].z, hop, 64);
            acc[k].w += __shfl_xor(acc[k].w, hop, 64);
        }
    }
    // d: full-wave sum (nonzero only on lanes 0,8,...,56)
    #pragma unroll
    for (int hop = 1; hop <= 32; hop <<= 1) d += __shfl_xor(d, hop, 64);

    __shared__ float sm[4], sd[4];
    __shared__ float so[4][128];
    if (lane == 0) { sm[w] = m; sd[w] = d; }
    if (lane < 8) {
        #pragma unroll
        for (int k = 0; k < 4; ++k) {
            so[w][lane * 16 + k * 4 + 0] = acc[k].x;
            so[w][lane * 16 + k * 4 + 1] = acc[k].y;
            so[w][lane * 16 + k * 4 + 2] = acc[k].z;
            so[w][lane * 16 + k * 4 + 3] = acc[k].w;
        }
    }
    __syncthreads();
    if (w == 0) {
        int cbase = h * 128 + 2 * lane;
        float M2 = fmaxf(fmaxf(sm[0], sm[1]), fmaxf(sm[2], sm[3]));
        float D = 0.f, Ox = 0.f, Oy = 0.f;
        #pragma unroll
        for (int ww = 0; ww < 4; ++ww) {
            float f = __expf(sm[ww] - M2);    // empty wave: exp(-inf)=0
            D  += sd[ww] * f;
            Ox += so[ww][2 * lane]     * f;
            Oy += so[ww][2 * lane + 1] * f;
        }
        float inv = 1.f / (D + 1e-16f);
        float r0 = Ox * inv + bias[cbase];
        float r1 = Oy * inv + bias[cbase + 1];
        if (mode) {
            r0 = fmaxf(r0, 0.f); r1 = fmaxf(r1, 0.f);
            ushort2 hi, lo;
            hi.x = f2bf(r0); lo.x = f2bf(r0 - bf2f(hi.x));
            hi.y = f2bf(r1); lo.y = f2bf(r1 - bf2f(hi.y));
            *(ushort2*)&poutp[(size_t)i * 1024 + cbase]          = hi;
            *(ushort2*)&poutp[(size_t)(MPAD + i) * 1024 + cbase] = lo;
        } else {
            float2 c0 = *(const float2*)&clfW[cbase];
            float2 c1 = *(const float2*)&clfW[1024 + cbase];
            float s0 = r0 * c0.x + r1 * c0.y;
            float s1 = r0 * c1.x + r1 * c1.y;
            #pragma unroll
            for (int off2 = 32; off2 > 0; off2 >>= 1) {
                s0 += __shfl_xor(s0, off2, 64);
                s1 += __shfl_xor(s1, off2, 64);
            }
            if (lane == 0) {
                float wgt = (i == 200) ? (1.f / 3.f) : (1.f / 300.f);
                atomicAdd(&outp[0], wgt * s0);
                atomicAdd(&outp[1], wgt * s1);
            }
        }
    }
}

extern "C" void kernel_launch(void* const* d_in, const int* in_sizes, int n_in,
                              void* d_out, int out_size, void* d_ws, size_t ws_size,
                              hipStream_t stream) {
    const float* x     = (const float*)d_in[0];
    const int*   eids  = (const int*)d_in[1];
    const float* W1l   = (const float*)d_in[2];
    const float* b1l   = (const float*)d_in[3];
    const float* W1r   = (const float*)d_in[4];
    const float* b1r   = (const float*)d_in[5];
    const float* att1  = (const float*)d_in[6];
    const float* bias1 = (const float*)d_in[7];
    const float* W2l   = (const float*)d_in[8];
    const float* b2l   = (const float*)d_in[9];
    const float* W2r   = (const float*)d_in[10];
    const float* b2r   = (const float*)d_in[11];
    const float* att2  = (const float*)d_in[12];
    const float* bias2 = (const float*)d_in[13];
    const float* clfW  = (const float*)d_in[14];
    const float* clfb  = (const float*)d_in[15];
    float* outp = (float*)d_out;

    int N = in_sizes[0] / 1024;   // 201
    int E = in_sizes[1] / 2;      // 40200
    int tot = E + N;
    int n8 = N * HEADS;           // 1608

    char* wsp = (char*)d_ws;
    int* offs   = (int*)wsp;  wsp += 1024;
    int* cursor = (int*)wsp;  wsp += 1024;
    int* srcs   = (int*)wsp;  wsp += ((size_t)(tot * 4 + 255) / 256) * 256;
    unsigned short* hpl = (unsigned short*)wsp;  wsp += 2 * MPAD * 1024 * 2;
    float* xlr1 = (float*)wsp;  wsp += (size_t)201 * 2048 * 4;
    float* xlr2 = (float*)wsp;  wsp += (size_t)201 * 2048 * 4;

    const int* srcA = eids;
    const int* dstA = eids + E;

    k_countscan<<<1, 1024, 0, stream>>>(dstA, E, N, offs, cursor, clfb, outp);
    k_scatter  <<<(tot + 255) / 256, 256, 0, stream>>>(srcA, dstA, E, N, cursor, srcs);

    k_gemm_mfma<0><<<256, 256, 0, stream>>>(x, (const unsigned short*)nullptr,
                                            W1l, b1l, W1r, b1r, xlr1);
    k_attn<<<n8, 256, 0, stream>>>(xlr1, att1, bias1, offs, srcs,
                                   hpl, (const float*)nullptr, (float*)nullptr, 1);
    k_gemm_mfma<1><<<256, 256, 0, stream>>>((const float*)nullptr, hpl,
                                            W2l, b2l, W2r, b2r, xlr2);
    k_attn<<<n8, 256, 0, stream>>>(xlr2, att2, bias2, offs, srcs,
                                   (unsigned short*)nullptr, clfW, outp, 0);
}

// Round 9
// 200.596 us; speedup vs baseline: 1.5834x; 1.3018x over previous
//
#include <hip/hip_runtime.h>
#include <hip/hip_bf16.h>

#define HEADS 8
#define MPAD  208   // padded node count (13*16)
#define KPAD  224   // padded s-dim (7*32)
#define HROWS 112   // rows per M-half in gemm
#define NB    208   // score blocks: 26 dtiles x 8 heads

typedef __attribute__((ext_vector_type(8))) short short8v;
typedef __attribute__((ext_vector_type(4))) float float4v;

static __device__ __forceinline__ unsigned short f2bf(float f) {
    unsigned int u = __float_as_uint(f);
    u += 0x7FFF + ((u >> 16) & 1);          // RNE
    return (unsigned short)(u >> 16);
}
static __device__ __forceinline__ float bf2f(unsigned short h) {
    return __uint_as_float(((unsigned int)h) << 16);
}

// ---------------- multiplicity matrix M[208][224] ----------------
__global__ void k_mzero(int* M) {
    int i = blockIdx.x * 1024 + threadIdx.x;
    if (i < MPAD * KPAD) M[i] = 0;
}

__global__ void k_mcount(const int* __restrict__ srcA, const int* __restrict__ dstA,
                         int E, int N, int* __restrict__ M) {
    int e = blockIdx.x * 256 + threadIdx.x;
    if (e < E + N) {
        int d = (e < E) ? dstA[e] : (e - E);   // self-loops appended
        int s = (e < E) ? srcA[e] : (e - E);
        atomicAdd(&M[d * KPAD + s], 1);
    }
}

// ---------------- MFMA split-bf16 dual GEMM, W-stationary ----------------
// Writes TRANSPOSED bf16 hi/lo planes: outT[2][2048][KPAD], outT[pl][col][row].
// MODE 0: A = fp32 x[201][1024]; MODE 1: A = bf16 planes [2][208][1024].
template<int MODE>
__global__ __launch_bounds__(256)
void k_gemm_mfma(const float* __restrict__ Xf, const unsigned short* __restrict__ Apl,
                 const float* __restrict__ Wl, const float* __restrict__ bl,
                 const float* __restrict__ Wr, const float* __restrict__ br,
                 unsigned short* __restrict__ outT) {
    __shared__ short lA[2 * HROWS * 40];
    __shared__ short lB[2 * 16 * 40];

    int tx = threadIdx.x;
    int panel = blockIdx.x >> 1;
    int half  = blockIdx.x & 1;
    int row0  = half * HROWS;
    int ntiles = half ? 6 : 7;
    int wv = tx >> 6, lane = tx & 63;
    int colpan = (panel & 63) * 16;
    const float* Wbase = (panel < 64) ? Wl : Wr;

    int gX[4], lX[4], rowv[4];
    #pragma unroll
    for (int j = 0; j < 4; ++j) {
        int idx = tx + 256 * j;
        if (MODE == 0) {
            int r = idx >> 3, seg = idx & 7;
            rowv[j] = row0 + r;
            gX[j] = (row0 + r) * 1024 + seg * 4;
            lX[j] = r * 40 + seg * 4;
        } else {
            int p = (idx >= 448);
            int rem = idx - p * 448;
            int r = rem >> 2, seg = rem & 3;
            rowv[j] = row0 + r;
            gX[j] = (p * MPAD + row0 + r) * 1024 + seg * 8;
            lX[j] = p * (HROWS * 40) + r * 40 + seg * 8;
        }
    }
    int wcol = tx >> 3, wseg = tx & 7;
    size_t goffW = (size_t)(colpan + wcol) * 1024 + wseg * 4;

    float4  af[4];
    short8v ap[4];
    float4  wreg;

    auto loadChunk = [&](int k0) {
        #pragma unroll
        for (int j = 0; j < 3; ++j) {
            if (MODE == 0) {
                af[j] = (rowv[j] < 201) ? *(const float4*)&Xf[gX[j] + k0]
                                        : make_float4(0.f, 0.f, 0.f, 0.f);
            } else {
                ap[j] = (rowv[j] < 201) ? *(const short8v*)&Apl[gX[j] + k0]
                                        : short8v{0,0,0,0,0,0,0,0};
            }
        }
        if (tx < 128) {
            if (MODE == 0) {
                af[3] = (rowv[3] < 201) ? *(const float4*)&Xf[gX[3] + k0]
                                        : make_float4(0.f, 0.f, 0.f, 0.f);
            } else {
                ap[3] = (rowv[3] < 201) ? *(const short8v*)&Apl[gX[3] + k0]
                                        : short8v{0,0,0,0,0,0,0,0};
            }
            wreg = *(const float4*)&Wbase[goffW + k0];
        }
    };
    auto storeSeg = [&](int j) {
        if (MODE == 0) {
            ushort4 hi, lo;
            hi.x = f2bf(af[j].x); lo.x = f2bf(af[j].x - bf2f(hi.x));
            hi.y = f2bf(af[j].y); lo.y = f2bf(af[j].y - bf2f(hi.y));
            hi.z = f2bf(af[j].z); lo.z = f2bf(af[j].z - bf2f(hi.z));
            hi.w = f2bf(af[j].w); lo.w = f2bf(af[j].w - bf2f(hi.w));
            *(ushort4*)&lA[lX[j]]              = hi;
            *(ushort4*)&lA[HROWS * 40 + lX[j]] = lo;
        } else {
            *(short8v*)&lA[lX[j]] = ap[j];
        }
    };
    auto storeChunk = [&]() {
        #pragma unroll
        for (int j = 0; j < 3; ++j) storeSeg(j);
        if (tx < 128) {
            storeSeg(3);
            ushort4 hi, lo;
            hi.x = f2bf(wreg.x); lo.x = f2bf(wreg.x - bf2f(hi.x));
            hi.y = f2bf(wreg.y); lo.y = f2bf(wreg.y - bf2f(hi.y));
            hi.z = f2bf(wreg.z); lo.z = f2bf(wreg.z - bf2f(hi.z));
            hi.w = f2bf(wreg.w); lo.w = f2bf(wreg.w - bf2f(hi.w));
            *(ushort4*)&lB[wcol * 40 + wseg * 4]        = hi;
            *(ushort4*)&lB[(16 + wcol) * 40 + wseg * 4] = lo;
        }
    };

    float4v acc[2] = {};
    int row16 = lane & 15;
    int k8    = (lane >> 4) * 8;

    loadChunk(0);
    for (int c = 0; c < 32; ++c) {
        __syncthreads();
        storeChunk();
        __syncthreads();
        if (c < 31) loadChunk((c + 1) * 32);
        short8v bh  = *(const short8v*)&lB[row16 * 40 + k8];
        short8v blo = *(const short8v*)&lB[(16 + row16) * 40 + k8];
        #pragma unroll
        for (int i = 0; i < 2; ++i) {
            int t = wv + 4 * i;
            if (t < ntiles) {
                short8v ah = *(const short8v*)&lA[(t * 16 + row16) * 40 + k8];
                short8v al = *(const short8v*)&lA[HROWS * 40 + (t * 16 + row16) * 40 + k8];
                acc[i] = __builtin_amdgcn_mfma_f32_16x16x32_bf16(ah, bh,  acc[i], 0, 0, 0);
                acc[i] = __builtin_amdgcn_mfma_f32_16x16x32_bf16(al, bh,  acc[i], 0, 0, 0);
                acc[i] = __builtin_amdgcn_mfma_f32_16x16x32_bf16(ah, blo, acc[i], 0, 0, 0);
            }
        }
    }

    // transposed hi/lo epilogue: outT[pl][colg][row], 4 consecutive rows -> ushort4
    int colg = panel * 16 + row16;
    float bias_val = ((panel < 64) ? bl : br)[colpan + row16];
    unsigned short* Th = outT;
    unsigned short* Tl = outT + (size_t)2048 * KPAD;
    #pragma unroll
    for (int i = 0; i < 2; ++i) {
        int t = wv + 4 * i;
        if (t < ntiles) {
            int rowb = row0 + t * 16 + (lane >> 4) * 4;
            ushort4 hi, lo;
            float v0 = acc[i][0] + bias_val, v1 = acc[i][1] + bias_val;
            float v2 = acc[i][2] + bias_val, v3 = acc[i][3] + bias_val;
            hi.x = f2bf(v0); lo.x = f2bf(v0 - bf2f(hi.x));
            hi.y = f2bf(v1); lo.y = f2bf(v1 - bf2f(hi.y));
            hi.z = f2bf(v2); lo.z = f2bf(v2 - bf2f(hi.z));
            hi.w = f2bf(v3); lo.w = f2bf(v3 - bf2f(hi.w));
            *(ushort4*)&Th[(size_t)colg * KPAD + rowb] = hi;
            *(ushort4*)&Tl[(size_t)colg * KPAD + rowb] = lo;
        }
    }
}

// ---------------- dense GATv2: scores + masked softmax + MFMA aggregation ----------------
// Block = (head h, dtile of 8 dsts). Thread t owns source s=t.
// LAYER1=1: relu + write hpl planes [2][208][1024]. LAYER1=0: classifier partials.
template<int LAYER1>
__global__ __launch_bounds__(256)
void k_score(const unsigned short* __restrict__ outT,  // [2][2048][KPAD]
             const float* __restrict__ att, const float* __restrict__ bias,
             const int* __restrict__ M,                // [208][224]
             unsigned short* __restrict__ hpl,
             const float* __restrict__ clfW, float* __restrict__ part) {
    __shared__ float xrt[8 * 128];
    __shared__ float a_l[128], a4_l[128];
    __shared__ float axr_l[8];
    __shared__ float Sm[8][256];
    __shared__ float smax_l[8], inv_l[8];
    __shared__ unsigned short aP[2][16][232];   // alpha hi/lo, row-stride 232 (2-way banks)
    __shared__ float ps[4][2];

    int tx = threadIdx.x;
    int bid = blockIdx.x;
    int h = bid & 7, dt = bid >> 3;            // dt < 26
    int w = tx >> 6, lane = tx & 63;
    const unsigned short* Th = outT;
    const unsigned short* Tl = outT + (size_t)2048 * KPAD;

    if (tx < 128) { float a = att[h * 128 + tx]; a_l[tx] = a; a4_l[tx] = 0.4f * a; }
    #pragma unroll
    for (int k = 0; k < 4; ++k) {              // stage xr tile (reconstructed fp32)
        int idx = tx + 256 * k;                // < 1024; c = idx>>3, j = idx&7
        int c = idx >> 3, j = idx & 7;
        size_t o = (size_t)(1024 + h * 128 + c) * KPAD + dt * 8 + j;
        xrt[j * 128 + c] = bf2f(Th[o]) + bf2f(Tl[o]);
    }
    for (int k = tx; k < 2 * 8 * 232; k += 256) {   // zero alpha rows 8..15
        int pl = k / (8 * 232), rem = k % (8 * 232);
        aP[pl][8 + rem / 232][rem % 232] = 0;
    }
    __syncthreads();
    if (tx < 64) {                              // axr[j] = <a, xr[j]>
        int j = tx >> 3, seg = tx & 7;
        float s = 0.f;
        for (int c = seg * 16; c < seg * 16 + 16; ++c) s += a_l[c] * xrt[j * 128 + c];
        s += __shfl_xor(s, 1, 64);
        s += __shfl_xor(s, 2, 64);
        s += __shfl_xor(s, 4, 64);
        if (seg == 0) axr_l[j] = s;
    }
    __syncthreads();

    // scores: S = 0.6*(axl+axr) + sum 0.4*a*|xl+xr|
    float sc[8] = {};
    float axl = 0.f;
    {
        size_t base = (size_t)(h * 128) * KPAD + tx;
        for (int c = 0; c < 128; ++c) {
            size_t o = base + (size_t)c * KPAD;
            float xv = bf2f(Th[o]) + bf2f(Tl[o]);
            axl = fmaf(a_l[c], xv, axl);
            #pragma unroll
            for (int j = 0; j < 8; ++j) {
                float t0 = xv + xrt[j * 128 + c];
                sc[j] = fmaf(a4_l[c], fabsf(t0), sc[j]);
            }
        }
    }
    float cnt[8];
    #pragma unroll
    for (int j = 0; j < 8; ++j) {
        float c_ = 0.f;
        if (tx < KPAD) c_ = (float)M[(dt * 8 + j) * KPAD + tx];
        cnt[j] = c_;
        sc[j] = 0.6f * (axl + axr_l[j]) + sc[j];
        Sm[j][tx] = (c_ > 0.f) ? sc[j] : -__builtin_huge_valf();
    }
    __syncthreads();
    #pragma unroll
    for (int rr = 0; rr < 2; ++rr) {            // masked row max
        int j = w * 2 + rr;
        float v = fmaxf(fmaxf(Sm[j][lane], Sm[j][lane + 64]),
                        fmaxf(Sm[j][lane + 128], Sm[j][lane + 192]));
        #pragma unroll
        for (int hop = 1; hop <= 32; hop <<= 1) v = fmaxf(v, __shfl_xor(v, hop, 64));
        if (lane == 0) smax_l[j] = v;
    }
    __syncthreads();
    float pj[8];
    #pragma unroll
    for (int j = 0; j < 8; ++j) {
        float p = (cnt[j] > 0.f) ? cnt[j] * __expf(sc[j] - smax_l[j]) : 0.f;
        pj[j] = p;
        Sm[j][tx] = p;
    }
    __syncthreads();
    #pragma unroll
    for (int rr = 0; rr < 2; ++rr) {            // denominators
        int j = w * 2 + rr;
        float v = Sm[j][lane] + Sm[j][lane + 64] + Sm[j][lane + 128] + Sm[j][lane + 192];
        #pragma unroll
        for (int hop = 1; hop <= 32; hop <<= 1) v += __shfl_xor(v, hop, 64);
        if (lane == 0) inv_l[j] = 1.f / (v + 1e-16f);
    }
    __syncthreads();
    if (tx < KPAD) {                            // alpha hi/lo
        #pragma unroll
        for (int j = 0; j < 8; ++j) {
            float a = pj[j] * inv_l[j];
            unsigned short hi = f2bf(a);
            unsigned short lo = f2bf(a - bf2f(hi));
            aP[0][j][tx] = hi;
            aP[1][j][tx] = lo;
        }
    }
    __syncthreads();

    // MFMA aggregation: C[16 d][32 c per wave] = alpha[16][224] @ xlT
    float4v acc[2] = {};
    int row16 = lane & 15;
    int k8 = (lane >> 4) * 8;
    for (int kc = 0; kc < 7; ++kc) {
        short8v Ah = *(const short8v*)&aP[0][row16][kc * 32 + k8];
        short8v Al = *(const short8v*)&aP[1][row16][kc * 32 + k8];
        #pragma unroll
        for (int cf = 0; cf < 2; ++cf) {
            int c_abs = h * 128 + w * 32 + cf * 16 + row16;
            size_t o = (size_t)c_abs * KPAD + kc * 32 + k8;
            short8v Bh = *(const short8v*)&Th[o];
            short8v Bl = *(const short8v*)&Tl[o];
            acc[cf] = __builtin_amdgcn_mfma_f32_16x16x32_bf16(Ah, Bh, acc[cf], 0, 0, 0);
            acc[cf] = __builtin_amdgcn_mfma_f32_16x16x32_bf16(Al, Bh, acc[cf], 0, 0, 0);
            acc[cf] = __builtin_amdgcn_mfma_f32_16x16x32_bf16(Ah, Bl, acc[cf], 0, 0, 0);
        }
    }

    int r = (lane >> 4) * 4;
    if (LAYER1) {
        if (r < 8) {
            #pragma unroll
            for (int cf = 0; cf < 2; ++cf) {
                int c_abs = h * 128 + w * 32 + cf * 16 + (lane & 15);
                float bv = bias[c_abs];
                #pragma unroll
                for (int j = 0; j < 4; ++j) {
                    int d = dt * 8 + r + j;
                    float val = fmaxf(acc[cf][j] + bv, 0.f);
                    unsigned short hi = f2bf(val);
                    unsigned short lo = f2bf(val - bf2f(hi));
                    hpl[(size_t)d * 1024 + c_abs]          = hi;
                    hpl[(size_t)(MPAD + d) * 1024 + c_abs] = lo;
                }
            }
        }
    } else {
        float p0 = 0.f, p1 = 0.f;
        if (r < 8) {
            #pragma unroll
            for (int cf = 0; cf < 2; ++cf) {
                int c_abs = h * 128 + w * 32 + cf * 16 + (lane & 15);
                float bv = bias[c_abs];
                float c0 = clfW[c_abs], c1 = clfW[1024 + c_abs];
                #pragma unroll
                for (int j = 0; j < 4; ++j) {
                    int d = dt * 8 + r + j;
                    if (d < 201) {
                        float val = acc[cf][j] + bv;
                        float wgt = (d == 200) ? (1.f / 3.f) : (1.f / 300.f);
                        p0 += wgt * val * c0;
                        p1 += wgt * val * c1;
                    }
                }
            }
        }
        #pragma unroll
        for (int hop = 1; hop <= 32; hop <<= 1) {
            p0 += __shfl_xor(p0, hop, 64);
            p1 += __shfl_xor(p1, hop, 64);
        }
        if (lane == 0) { ps[w][0] = p0; ps[w][1] = p1; }
        __syncthreads();
        if (tx == 0) {
            part[bid]      = ps[0][0] + ps[1][0] + ps[2][0] + ps[3][0];
            part[NB + bid] = ps[0][1] + ps[1][1] + ps[2][1] + ps[3][1];
        }
    }
}

// ---------------- finalize ----------------
__global__ __launch_bounds__(256)
void k_fin(const float* __restrict__ part, const float* __restrict__ clfb,
           float* __restrict__ outp) {
    int t = threadIdx.x;
    float s0 = (t < NB) ? part[t] : 0.f;
    float s1 = (t < NB) ? part[NB + t] : 0.f;
    __shared__ float r0[256], r1[256];
    r0[t] = s0; r1[t] = s1;
    __syncthreads();
    for (int off = 128; off > 0; off >>= 1) {
        if (t < off) { r0[t] += r0[t + off]; r1[t] += r1[t + off]; }
        __syncthreads();
    }
    if (t == 0) { outp[0] = r0[0] + clfb[0]; outp[1] = r0[0] * 0.f + r1[0] + clfb[1]; }
}

extern "C" void kernel_launch(void* const* d_in, const int* in_sizes, int n_in,
                              void* d_out, int out_size, void* d_ws, size_t ws_size,
                              hipStream_t stream) {
    const float* x     = (const float*)d_in[0];
    const int*   eids  = (const int*)d_in[1];
    const float* W1l   = (const float*)d_in[2];
    const float* b1l   = (const float*)d_in[3];
    const float* W1r   = (const float*)d_in[4];
    const float* b1r   = (const float*)d_in[5];
    const float* att1  = (const float*)d_in[6];
    const float* bias1 = (const float*)d_in[7];
    const float* W2l   = (const float*)d_in[8];
    const float* b2l   = (const float*)d_in[9];
    const float* W2r   = (const float*)d_in[10];
    const float* b2r   = (const float*)d_in[11];
    const float* att2  = (const float*)d_in[12];
    const float* bias2 = (const float*)d_in[13];
    const float* clfW  = (const float*)d_in[14];
    const float* clfb  = (const float*)d_in[15];
    float* outp = (float*)d_out;

    int N = in_sizes[0] / 1024;   // 201
    int E = in_sizes[1] / 2;      // 40200
    int tot = E + N;

    char* wsp = (char*)d_ws;
    int* M = (int*)wsp;                         wsp += (size_t)MPAD * KPAD * 4;
    unsigned short* outT1 = (unsigned short*)wsp; wsp += (size_t)2 * 2048 * KPAD * 2;
    unsigned short* hpl   = (unsigned short*)wsp; wsp += (size_t)2 * MPAD * 1024 * 2;
    unsigned short* outT2 = (unsigned short*)wsp; wsp += (size_t)2 * 2048 * KPAD * 2;
    float* part = (float*)wsp;                   wsp += (size_t)2 * NB * 4;

    const int* srcA = eids;
    const int* dstA = eids + E;

    k_mzero <<<(MPAD * KPAD + 1023) / 1024, 1024, 0, stream>>>(M);
    k_mcount<<<(tot + 255) / 256, 256, 0, stream>>>(srcA, dstA, E, N, M);

    k_gemm_mfma<0><<<256, 256, 0, stream>>>(x, (const unsigned short*)nullptr,
                                            W1l, b1l, W1r, b1r, outT1);
    k_score<1><<<NB, 256, 0, stream>>>(outT1, att1, bias1, M,
                                       hpl, (const float*)nullptr, (float*)nullptr);
    k_gemm_mfma<1><<<256, 256, 0, stream>>>((const float*)nullptr, hpl,
                                            W2l, b2l, W2r, b2r, outT2);
    k_score<0><<<NB, 256, 0, stream>>>(outT2, att2, bias2, M,
                                       (unsigned short*)nullptr, clfW, part);
    k_fin<<<1, 256, 0, stream>>>(part, clfb, outp);
}